// Round 1
// baseline (127.858 us; speedup 1.0000x reference)
//
#include <hip/hip_runtime.h>
#include <math.h>

namespace {
constexpr int Bn = 8;
constexpr int Ln = 8192;
constexpr int Rn = 64;
constexpr int Hn = 512;
constexpr int LT = 128;
constexpr int NSEG = Ln / LT;            // 64 segments per batch
constexpr int NK1 = Bn * NSEG;           // 512 k1 blocks

// workspace float offsets
constexpr size_t PS        = 8352;       // per-k1-block partial stride: A1[4096] A2[4096] u1[64] u2[64] sig[2] pad
constexpr size_t OFF_G     = 0;                                   // 64x64
constexpr size_t OFF_W     = 4096;                                // 64
constexpr size_t OFF_BB    = 4160;                                // 1 (+pad)
constexpr size_t OFF_STATS = 4224;                                // NK1 * PS
constexpr size_t OFF_T2    = OFF_STATS + (size_t)NK1 * PS;        // B*64*H
constexpr size_t OFF_T1    = OFF_T2 + (size_t)Bn * 64 * Hn;       // B*64*H
constexpr size_t OFF_P1    = OFF_T1 + (size_t)Bn * 64 * Hn;       // B*H
constexpr size_t OFF_P2    = OFF_P1 + (size_t)Bn * Hn;            // B*H
constexpr size_t OFF_Q1    = OFF_P2 + (size_t)Bn * Hn;            // B*H
constexpr size_t OFF_SIG   = OFF_Q1 + (size_t)Bn * Hn;            // B*2 (+pad to 64)
constexpr size_t OFF_UP    = OFF_SIG + 64;                        // B*4*64*H  (U h-quarter partials)
constexpr size_t OFF_C1P   = OFF_UP + (size_t)Bn * 4 * 64 * Hn;   // B*4*H
constexpr size_t OFF_GP    = OFF_C1P + (size_t)Bn * 4 * Hn;       // B*4*H
constexpr size_t OFF_TD    = OFF_GP + (size_t)Bn * 4 * Hn;        // B*64*H
constexpr size_t OFF_A1R   = OFF_TD + (size_t)Bn * 64 * Hn;       // B*4096
constexpr size_t OFF_A2R   = OFF_A1R + (size_t)Bn * 4096;         // B*4096
constexpr size_t OFF_U1R   = OFF_A2R + (size_t)Bn * 4096;         // B*64
constexpr size_t OFF_U2R   = OFF_U1R + (size_t)Bn * 64;           // B*64
}

// ---------------------------------------------------------------------------
// k0: G = Wk*Wk^T [64x64], w = Wk*bk [64], bb = bk.bk
// grid 17 x 256
__global__ __launch_bounds__(256) void k0_pre(const float* __restrict__ Wk,
                                              const float* __restrict__ bk,
                                              float* __restrict__ ws) {
  const int t = threadIdx.x;
  const int blk = blockIdx.x;
  if (blk < 16) {
    const int e = blk * 256 + t;
    const int i = e >> 6, j = e & 63;
    const float4* a4 = (const float4*)(Wk + (size_t)i * Hn);
    const float4* b4 = (const float4*)(Wk + (size_t)j * Hn);
    float s0 = 0.f, s1 = 0.f, s2 = 0.f, s3 = 0.f;
    for (int h = 0; h < Hn / 4; ++h) {
      float4 x = a4[h], y = b4[h];
      s0 += x.x * y.x; s1 += x.y * y.y; s2 += x.z * y.z; s3 += x.w * y.w;
    }
    ws[OFF_G + e] = (s0 + s1) + (s2 + s3);
  } else {
    if (t < 64) {
      float s = 0.f;
      for (int h = 0; h < Hn; ++h) s += Wk[(size_t)t * Hn + h] * bk[h];
      ws[OFF_W + t] = s;
    } else if (t == 64) {
      float s = 0.f;
      for (int h = 0; h < Hn; ++h) s += bk[h] * bk[h];
      ws[OFF_BB] = s;
    }
  }
}

// ---------------------------------------------------------------------------
// k1: per 128-row tile: row norms via x*G*x + 2x.w + bb, then accumulate
//     A1 = X^T D X, A2 = X^T D^2 X, u1, u2, sig partials.
// grid 512 (= 8 b x 64 seg) x 256
__global__ __launch_bounds__(256) void k1_stats(const float* __restrict__ hs,
                                                float* __restrict__ ws) {
  __shared__ __align__(16) float XT[64][132];   // [r][l], padded
  __shared__ __align__(16) float Gs[64][64];
  __shared__ __align__(16) float wsh[64];
  __shared__ __align__(16) float n2p[8][LT];
  __shared__ __align__(16) float d1s[LT];
  __shared__ __align__(16) float d2s[LT];

  const int t = threadIdx.x;
  const int blk = blockIdx.x;
  const int b = blk >> 6;
  const int seg = blk & 63;

  for (int k = 0; k < 16; ++k) {
    int e = k * 256 + t;
    (&Gs[0][0])[e] = ws[OFF_G + e];
  }
  if (t < 64) wsh[t] = ws[OFF_W + t];
  const float bb = ws[OFF_BB];

  // stage X transposed: XT[r][l]
  {
    const float4* src = (const float4*)(hs + ((size_t)b * Ln + (size_t)seg * LT) * Rn);
    #pragma unroll
    for (int k = 0; k < 8; ++k) {
      int f = k * 256 + t;
      float4 v = src[f];
      int l = f >> 4, j0 = (f & 15) << 2;
      XT[j0 + 0][l] = v.x; XT[j0 + 1][l] = v.y; XT[j0 + 2][l] = v.z; XT[j0 + 3][l] = v.w;
    }
  }
  __syncthreads();

  // phase A: Y[i][l] = sum_k G[i][k]*XT[k][l]; n2 partials
  {
    const int i0 = (t & 7) * 8;
    const int la = (t >> 3) * 4;
    float acc[8][4] = {};
    for (int k = 0; k < 64; ++k) {
      const float4 g0 = *(const float4*)&Gs[k][i0];
      const float4 g1 = *(const float4*)&Gs[k][i0 + 4];
      const float4 xv = *(const float4*)&XT[k][la];
      const float ga[8] = {g0.x, g0.y, g0.z, g0.w, g1.x, g1.y, g1.z, g1.w};
      const float xa[4] = {xv.x, xv.y, xv.z, xv.w};
      #pragma unroll
      for (int a = 0; a < 8; ++a)
        #pragma unroll
        for (int lv = 0; lv < 4; ++lv)
          acc[a][lv] += ga[a] * xa[lv];
    }
    #pragma unroll
    for (int lv = 0; lv < 4; ++lv) {
      float s = 0.f;
      #pragma unroll
      for (int a = 0; a < 8; ++a)
        s += XT[i0 + a][la + lv] * (acc[a][lv] + 2.0f * wsh[i0 + a]);
      n2p[t & 7][la + lv] = s;
    }
  }
  __syncthreads();
  if (t < LT) {
    float n2 = bb;
    #pragma unroll
    for (int p = 0; p < 8; ++p) n2 += n2p[p][t];
    n2 = fmaxf(n2, 0.0f);
    const float d1 = 1.0f / fmaxf(sqrtf(n2), 1e-12f);
    d1s[t] = d1;
    d2s[t] = d1 * d1;
  }
  __syncthreads();

  float sg1 = 0.f, sg2 = 0.f;
  if (t == 0) {
    for (int l = 0; l < LT; ++l) { sg1 += d1s[l]; sg2 += d2s[l]; }
  }

  // phase B: A1/A2 4x4 per-thread accumulation over the tile
  const int bi0 = (t >> 4) * 4;
  const int bj0 = (t & 15) * 4;
  float A1a[4][4] = {}, A2a[4][4] = {};
  float u1a[4] = {0.f, 0.f, 0.f, 0.f}, u2a[4] = {0.f, 0.f, 0.f, 0.f};
  for (int l4 = 0; l4 < LT; l4 += 4) {
    const float4 q1 = *(const float4*)&d1s[l4];
    const float4 q2 = *(const float4*)&d2s[l4];
    const float d1v[4] = {q1.x, q1.y, q1.z, q1.w};
    const float d2v[4] = {q2.x, q2.y, q2.z, q2.w};
    float e1[4][4], e2[4][4], xj[4][4];
    #pragma unroll
    for (int a = 0; a < 4; ++a) {
      const float4 xv = *(const float4*)&XT[bi0 + a][l4];
      const float xa[4] = {xv.x, xv.y, xv.z, xv.w};
      #pragma unroll
      for (int lv = 0; lv < 4; ++lv) {
        e1[a][lv] = d1v[lv] * xa[lv];
        e2[a][lv] = d2v[lv] * xa[lv];
      }
    }
    #pragma unroll
    for (int bq = 0; bq < 4; ++bq) {
      const float4 xv = *(const float4*)&XT[bj0 + bq][l4];
      xj[bq][0] = xv.x; xj[bq][1] = xv.y; xj[bq][2] = xv.z; xj[bq][3] = xv.w;
    }
    #pragma unroll
    for (int a = 0; a < 4; ++a)
      #pragma unroll
      for (int bq = 0; bq < 4; ++bq) {
        float s1 = A1a[a][bq], s2 = A2a[a][bq];
        #pragma unroll
        for (int lv = 0; lv < 4; ++lv) {
          s1 += e1[a][lv] * xj[bq][lv];
          s2 += e2[a][lv] * xj[bq][lv];
        }
        A1a[a][bq] = s1; A2a[a][bq] = s2;
      }
    if (bj0 == 0) {
      #pragma unroll
      for (int a = 0; a < 4; ++a)
        #pragma unroll
        for (int lv = 0; lv < 4; ++lv) {
          u1a[a] += e1[a][lv];
          u2a[a] += e2[a][lv];
        }
    }
  }

  float* P = ws + OFF_STATS + (size_t)blk * PS;
  #pragma unroll
  for (int a = 0; a < 4; ++a)
    #pragma unroll
    for (int bq = 0; bq < 4; ++bq) {
      P[(bi0 + a) * 64 + bj0 + bq] = A1a[a][bq];
      P[4096 + (bi0 + a) * 64 + bj0 + bq] = A2a[a][bq];
    }
  if (bj0 == 0) {
    #pragma unroll
    for (int a = 0; a < 4; ++a) {
      P[8192 + bi0 + a] = u1a[a];
      P[8256 + bi0 + a] = u2a[a];
    }
  }
  if (t == 0) { P[8320] = sg1; P[8321] = sg2; }
}

// ---------------------------------------------------------------------------
// k1b: reduce 64 partials per batch -> A1R, A2R, U1R, U2R, SIG
// grid 64 (= b(8) x sel(2) x q(4)) x 256
__global__ __launch_bounds__(256) void k1b_reduce(float* __restrict__ ws) {
  const int t = threadIdx.x;
  const int blk = blockIdx.x;
  const int b = blk >> 3, sel = (blk >> 2) & 1, q = blk & 3;
  const float* SB = ws + OFF_STATS + (size_t)b * 64 * PS + (size_t)sel * 4096;
  float* dst = ws + (sel ? OFF_A2R : OFF_A1R) + (size_t)b * 4096;
  #pragma unroll
  for (int k = 0; k < 4; ++k) {
    const int e = q * 1024 + k * 256 + t;
    float s = 0.f;
    for (int p = 0; p < 64; ++p) s += SB[(size_t)p * PS + e];
    dst[e] = s;
  }
  if (sel == 0 && q == 0) {
    const float* UB = ws + OFF_STATS + (size_t)b * 64 * PS;
    if (t < 64) {
      float s = 0.f;
      for (int p = 0; p < 64; ++p) s += UB[(size_t)p * PS + 8192 + t];
      ws[OFF_U1R + b * 64 + t] = s;
    } else if (t < 128) {
      const int i = t - 64;
      float s = 0.f;
      for (int p = 0; p < 64; ++p) s += UB[(size_t)p * PS + 8256 + i];
      ws[OFF_U2R + b * 64 + i] = s;
    } else if (t == 128) {
      float s1 = 0.f, s2 = 0.f;
      for (int p = 0; p < 64; ++p) {
        s1 += UB[(size_t)p * PS + 8320];
        s2 += UB[(size_t)p * PS + 8321];
      }
      ws[OFF_SIG + b * 2] = s1;
      ws[OFF_SIG + b * 2 + 1] = s2;
    }
  }
}

// ---------------------------------------------------------------------------
// k2a: T2 = A2 @ Wk, T1 = A1 @ Wv; p1 = Wk^T u1, p2 = Wk^T u2, q1 = Wv^T u1
// grid 64 (= b(8) x wsel(2) x hstrip(4)) x 256
__global__ __launch_bounds__(256) void k2a_T(const float* __restrict__ Wk,
                                             const float* __restrict__ Wv,
                                             float* __restrict__ ws) {
  __shared__ __align__(16) float A[64][65];
  const int t = threadIdx.x;
  const int blk = blockIdx.x;
  const int b = blk >> 3, wsel = (blk >> 2) & 1, hstrip = blk & 3;
  const int hs0 = hstrip * 128;
  const float* Ar = ws + (wsel ? OFF_A1R : OFF_A2R) + (size_t)b * 4096;
  for (int k = 0; k < 16; ++k) {
    const int e = k * 256 + t;
    A[e >> 6][e & 63] = Ar[e];
  }
  __syncthreads();
  const float* W = wsel ? Wv : Wk;
  float* T = ws + (wsel ? OFF_T1 : OFF_T2) + (size_t)b * 64 * Hn;
  const int ti = t >> 4, th = t & 15;
  float acc[4][8] = {};
  for (int j = 0; j < 64; ++j) {
    float av[4];
    #pragma unroll
    for (int a = 0; a < 4; ++a) av[a] = A[ti * 4 + a][j];
    #pragma unroll
    for (int hb = 0; hb < 8; ++hb) {
      const float wv = W[(size_t)j * Hn + hs0 + hb * 16 + th];
      #pragma unroll
      for (int a = 0; a < 4; ++a) acc[a][hb] += av[a] * wv;
    }
  }
  #pragma unroll
  for (int a = 0; a < 4; ++a)
    #pragma unroll
    for (int hb = 0; hb < 8; ++hb)
      T[(size_t)(ti * 4 + a) * Hn + hs0 + hb * 16 + th] = acc[a][hb];

  // rank-1 helper vectors, each block handles its own 128-h strip
  if (t < 128) {
    const int h = hs0 + t;
    const float* u1r = ws + OFF_U1R + b * 64;
    const float* u2r = ws + OFF_U2R + b * 64;
    if (wsel == 0) {
      float s1 = 0.f, s2 = 0.f;
      for (int i = 0; i < 64; ++i) {
        const float wv = Wk[(size_t)i * Hn + h];
        s1 += wv * u1r[i];
        s2 += wv * u2r[i];
      }
      ws[OFF_P1 + b * Hn + h] = s1;
      ws[OFF_P2 + b * Hn + h] = s2;
    } else {
      float s = 0.f;
      for (int i = 0; i < 64; ++i) s += Wv[(size_t)i * Hn + h] * u1r[i];
      ws[OFF_Q1 + b * Hn + h] = s;
    }
  }
}

// ---------------------------------------------------------------------------
// k3: U partials = T2 @ C (h-quarter split), plus c1 = bk^T C, g = p2^T C
// grid 256 (= b(8) x hq(4) x dstrip(8)) x 256
__global__ __launch_bounds__(256) void k3_U(const float* __restrict__ C,
                                            const float* __restrict__ bk,
                                            float* __restrict__ ws) {
  const int t = threadIdx.x;
  const int blk = blockIdx.x;
  const int b = blk >> 5;
  const int rem = blk & 31;
  const int hq = rem >> 3;
  const int ds0 = (rem & 7) * 64;
  const int ti = t >> 4;   // i = ti*4+a
  const int td = t & 15;   // d = ds0 + td + 16*db
  const float* T2 = ws + OFF_T2 + (size_t)b * 64 * Hn;
  const float* Cb = C + (size_t)b * Hn * Hn;
  const float* p2 = ws + OFF_P2 + (size_t)b * Hn;
  float acc[4][4] = {};
  float c1a[4] = {0.f, 0.f, 0.f, 0.f}, ga[4] = {0.f, 0.f, 0.f, 0.f};
  const int h0 = hq * 128;
  for (int h = h0; h < h0 + 128; ++h) {
    float tv[4];
    #pragma unroll
    for (int a = 0; a < 4; ++a) tv[a] = T2[(size_t)(ti * 4 + a) * Hn + h];
    float cv[4];
    #pragma unroll
    for (int db = 0; db < 4; ++db) cv[db] = Cb[(size_t)h * Hn + ds0 + db * 16 + td];
    #pragma unroll
    for (int a = 0; a < 4; ++a)
      #pragma unroll
      for (int db = 0; db < 4; ++db) acc[a][db] += tv[a] * cv[db];
    if (ti == 0) {
      const float bkh = bk[h], p2h = p2[h];
      #pragma unroll
      for (int db = 0; db < 4; ++db) { c1a[db] += bkh * cv[db]; ga[db] += p2h * cv[db]; }
    }
  }
  float* Up = ws + OFF_UP + (size_t)(b * 4 + hq) * 64 * Hn;
  #pragma unroll
  for (int a = 0; a < 4; ++a)
    #pragma unroll
    for (int db = 0; db < 4; ++db)
      Up[(size_t)(ti * 4 + a) * Hn + ds0 + db * 16 + td] = acc[a][db];
  if (ti == 0) {
    float* c1p = ws + OFF_C1P + (size_t)(b * 4 + hq) * Hn;
    float* gp = ws + OFF_GP + (size_t)(b * 4 + hq) * Hn;
    #pragma unroll
    for (int db = 0; db < 4; ++db) {
      c1p[ds0 + db * 16 + td] = c1a[db];
      gp[ds0 + db * 16 + td] = ga[db];
    }
  }
}

// ---------------------------------------------------------------------------
// k3b: Td = T1 - sum_q Up[q]  (elementwise, float4)
// grid 256 x 256
__global__ __launch_bounds__(256) void k3b_td(float* __restrict__ ws) {
  const int f = blockIdx.x * 256 + threadIdx.x;   // float4 index, 65536 total
  const int b = f >> 13;
  const int r4 = f & 8191;
  const float4* T14 = (const float4*)(ws + OFF_T1);
  const float4* Up4 = (const float4*)(ws + OFF_UP);
  float4 v = T14[f];
  #pragma unroll
  for (int q = 0; q < 4; ++q) {
    const float4 u = Up4[(size_t)(b * 4 + q) * 8192 + r4];
    v.x -= u.x; v.y -= u.y; v.z -= u.z; v.w -= u.w;
  }
  ((float4*)(ws + OFF_TD))[f] = v;
}

// ---------------------------------------------------------------------------
// k4: out = C + Wk^T Td + (p1 + sig1*bk) (x) bv + bk (x) (q1 - g - sig2*c1) - p2 (x) c1
// grid 256 (= b(8) x hstrip(8, 64-wide) x dstrip(4, 128-wide)) x 256
__global__ __launch_bounds__(256) void k4_out(const float* __restrict__ C,
                                              const float* __restrict__ Wk,
                                              const float* __restrict__ bk,
                                              const float* __restrict__ bv,
                                              const float* __restrict__ ws,
                                              float* __restrict__ out) {
  __shared__ __align__(16) float Td[64][132];
  __shared__ __align__(16) float Wks[64][65];
  __shared__ __align__(16) float phs[64];
  __shared__ __align__(16) float bks[64];
  __shared__ __align__(16) float p2s[64];
  __shared__ __align__(16) float bvs[128];
  __shared__ __align__(16) float terms[128];
  __shared__ __align__(16) float c1s[128];

  const int t = threadIdx.x;
  const int blk = blockIdx.x;
  const int b = blk >> 5;
  const int hs0 = ((blk >> 2) & 7) * 64;
  const int d0 = (blk & 3) * 128;
  const float sg1 = ws[OFF_SIG + b * 2];
  const float sg2 = ws[OFF_SIG + b * 2 + 1];

  const float* TdG = ws + OFF_TD + (size_t)b * 64 * Hn;
  for (int k = 0; k < 32; ++k) {
    const int e = k * 256 + t;
    const int j = e >> 7, dd = e & 127;
    Td[j][dd] = TdG[(size_t)j * Hn + d0 + dd];
  }
  for (int k = 0; k < 16; ++k) {
    const int e = k * 256 + t;
    const int j = e >> 6, hh = e & 63;
    Wks[j][hh] = Wk[(size_t)j * Hn + hs0 + hh];
  }
  if (t < 64) {
    const int h = hs0 + t;
    const float bkv = bk[h];
    bks[t] = bkv;
    phs[t] = ws[OFF_P1 + (size_t)b * Hn + h] + sg1 * bkv;
    p2s[t] = ws[OFF_P2 + (size_t)b * Hn + h];
  } else if (t < 192) {
    const int dd = t - 64;
    const int d = d0 + dd;
    float c1 = 0.f, g = 0.f;
    #pragma unroll
    for (int q = 0; q < 4; ++q) {
      c1 += ws[OFF_C1P + (size_t)(b * 4 + q) * Hn + d];
      g += ws[OFF_GP + (size_t)(b * 4 + q) * Hn + d];
    }
    c1s[dd] = c1;
    bvs[dd] = bv[d];
    terms[dd] = ws[OFF_Q1 + (size_t)b * Hn + d] - g - sg2 * c1;
  }
  __syncthreads();

  const int ti = t >> 4;  // h = hs0 + ti*4+a
  const int tj = t & 15;  // d = d0 + tj + 16*db
  float acc[4][8] = {};
  for (int j = 0; j < 64; ++j) {
    float wv[4];
    #pragma unroll
    for (int a = 0; a < 4; ++a) wv[a] = Wks[j][ti * 4 + a];
    float tdv[8];
    #pragma unroll
    for (int db = 0; db < 8; ++db) tdv[db] = Td[j][tj + db * 16];
    #pragma unroll
    for (int a = 0; a < 4; ++a)
      #pragma unroll
      for (int db = 0; db < 8; ++db) acc[a][db] += wv[a] * tdv[db];
  }

  const float* Cb = C + (size_t)b * Hn * Hn;
  float* outb = out + (size_t)b * Hn * Hn;
  #pragma unroll
  for (int a = 0; a < 4; ++a) {
    const int hh = ti * 4 + a;
    const int h = hs0 + hh;
    const float bkh = bks[hh], ph = phs[hh], p2h = p2s[hh];
    #pragma unroll
    for (int db = 0; db < 8; ++db) {
      const int dd = tj + db * 16;
      const int d = d0 + dd;
      const float v = Cb[(size_t)h * Hn + d] + acc[a][db] + ph * bvs[dd] +
                      bkh * terms[dd] - p2h * c1s[dd];
      outb[(size_t)h * Hn + d] = v;
    }
  }
}

// ---------------------------------------------------------------------------
extern "C" void kernel_launch(void* const* d_in, const int* in_sizes, int n_in,
                              void* d_out, int out_size, void* d_ws, size_t ws_size,
                              hipStream_t stream) {
  const float* hs = (const float*)d_in[0];
  const float* C  = (const float*)d_in[1];
  const float* Wk = (const float*)d_in[2];
  const float* bk = (const float*)d_in[3];
  const float* Wv = (const float*)d_in[4];
  const float* bv = (const float*)d_in[5];
  float* out = (float*)d_out;
  float* ws = (float*)d_ws;
  (void)in_sizes; (void)n_in; (void)out_size; (void)ws_size;

  hipLaunchKernelGGL(k0_pre,   dim3(17),  dim3(256), 0, stream, Wk, bk, ws);
  hipLaunchKernelGGL(k1_stats, dim3(512), dim3(256), 0, stream, hs, ws);
  hipLaunchKernelGGL(k1b_reduce, dim3(64), dim3(256), 0, stream, ws);
  hipLaunchKernelGGL(k2a_T,    dim3(64),  dim3(256), 0, stream, Wk, Wv, ws);
  hipLaunchKernelGGL(k3_U,     dim3(256), dim3(256), 0, stream, C, bk, ws);
  hipLaunchKernelGGL(k3b_td,   dim3(256), dim3(256), 0, stream, ws);
  hipLaunchKernelGGL(k4_out,   dim3(256), dim3(256), 0, stream, C, Wk, bk, bv, ws, out);
}

// Round 2
// 98.389 us; speedup vs baseline: 1.2995x; 1.2995x over previous
//
#include <hip/hip_runtime.h>
#include <math.h>

namespace {
constexpr int Bn = 8;
constexpr int Ln = 8192;
constexpr int Rn = 64;
constexpr int Hn = 512;
constexpr int LT = 128;
constexpr int NSEG = Ln / LT;            // 64 segments per batch
constexpr int NK1 = Bn * NSEG;           // 512 k1 blocks
constexpr int NH3 = 16;                  // k3 h-chunks (32 h each)

// workspace float offsets
constexpr size_t PS        = 8352;       // per-k1-block partial stride: A1[4096] A2[4096] u1[64] u2[64] sig[2] pad
constexpr size_t OFF_G     = 0;                                   // 64x64
constexpr size_t OFF_W     = 4096;                                // 64
constexpr size_t OFF_BB    = 4160;                                // 1 (+pad)
constexpr size_t OFF_STATS = 4224;                                // NK1 * PS
constexpr size_t OFF_T2    = OFF_STATS + (size_t)NK1 * PS;        // B*64*H
constexpr size_t OFF_T1    = OFF_T2 + (size_t)Bn * 64 * Hn;       // B*64*H
constexpr size_t OFF_P1    = OFF_T1 + (size_t)Bn * 64 * Hn;       // B*H
constexpr size_t OFF_P2    = OFF_P1 + (size_t)Bn * Hn;            // B*H
constexpr size_t OFF_Q1    = OFF_P2 + (size_t)Bn * Hn;            // B*H
constexpr size_t OFF_SIG   = OFF_Q1 + (size_t)Bn * Hn;            // B*2 (+pad to 64)
constexpr size_t OFF_UP    = OFF_SIG + 64;                        // B*NH3*64*H  (U h-chunk partials)
constexpr size_t OFF_C1P   = OFF_UP + (size_t)Bn * NH3 * 64 * Hn; // B*NH3*H
constexpr size_t OFF_GP    = OFF_C1P + (size_t)Bn * NH3 * Hn;     // B*NH3*H
constexpr size_t OFF_TD    = OFF_GP + (size_t)Bn * NH3 * Hn;      // B*64*H
constexpr size_t OFF_A1R   = OFF_TD + (size_t)Bn * 64 * Hn;       // B*4096
constexpr size_t OFF_A2R   = OFF_A1R + (size_t)Bn * 4096;         // B*4096
constexpr size_t OFF_U1R   = OFF_A2R + (size_t)Bn * 4096;         // B*64
constexpr size_t OFF_U2R   = OFF_U1R + (size_t)Bn * 64;           // B*64
}

// ---------------------------------------------------------------------------
// k0: G = Wk*Wk^T [64x64], w = Wk*bk [64], bb = bk.bk
// grid 17 x 256
__global__ __launch_bounds__(256) void k0_pre(const float* __restrict__ Wk,
                                              const float* __restrict__ bk,
                                              float* __restrict__ ws) {
  const int t = threadIdx.x;
  const int blk = blockIdx.x;
  if (blk < 16) {
    const int e = blk * 256 + t;
    const int i = e >> 6, j = e & 63;
    const float4* a4 = (const float4*)(Wk + (size_t)i * Hn);
    const float4* b4 = (const float4*)(Wk + (size_t)j * Hn);
    float s0 = 0.f, s1 = 0.f, s2 = 0.f, s3 = 0.f;
    for (int h = 0; h < Hn / 4; ++h) {
      float4 x = a4[h], y = b4[h];
      s0 += x.x * y.x; s1 += x.y * y.y; s2 += x.z * y.z; s3 += x.w * y.w;
    }
    ws[OFF_G + e] = (s0 + s1) + (s2 + s3);
  } else {
    if (t < 64) {
      float s = 0.f;
      for (int h = 0; h < Hn; ++h) s += Wk[(size_t)t * Hn + h] * bk[h];
      ws[OFF_W + t] = s;
    } else if (t == 64) {
      float s = 0.f;
      for (int h = 0; h < Hn; ++h) s += bk[h] * bk[h];
      ws[OFF_BB] = s;
    }
  }
}

// ---------------------------------------------------------------------------
// k1: per 128-row tile: row norms via x*G*x + 2x.w + bb, then accumulate
//     A1 = X^T D X, A2 = X^T D^2 X, u1, u2, sig partials.
// grid 512 (= 8 b x 64 seg) x 256
__global__ __launch_bounds__(256) void k1_stats(const float* __restrict__ hs,
                                                float* __restrict__ ws) {
  __shared__ __align__(16) float XT[64][132];   // [r][l], padded
  __shared__ __align__(16) float Gs[64][64];
  __shared__ __align__(16) float wsh[64];
  __shared__ __align__(16) float n2p[8][LT];
  __shared__ __align__(16) float d1s[LT];
  __shared__ __align__(16) float d2s[LT];

  const int t = threadIdx.x;
  const int blk = blockIdx.x;
  const int b = blk >> 6;
  const int seg = blk & 63;

  for (int k = 0; k < 16; ++k) {
    int e = k * 256 + t;
    (&Gs[0][0])[e] = ws[OFF_G + e];
  }
  if (t < 64) wsh[t] = ws[OFF_W + t];
  const float bb = ws[OFF_BB];

  // stage X transposed: XT[r][l]
  {
    const float4* src = (const float4*)(hs + ((size_t)b * Ln + (size_t)seg * LT) * Rn);
    #pragma unroll
    for (int k = 0; k < 8; ++k) {
      int f = k * 256 + t;
      float4 v = src[f];
      int l = f >> 4, j0 = (f & 15) << 2;
      XT[j0 + 0][l] = v.x; XT[j0 + 1][l] = v.y; XT[j0 + 2][l] = v.z; XT[j0 + 3][l] = v.w;
    }
  }
  __syncthreads();

  // phase A: Y[i][l] = sum_k G[i][k]*XT[k][l]; n2 partials
  {
    const int i0 = (t & 7) * 8;
    const int la = (t >> 3) * 4;
    float acc[8][4] = {};
    for (int k = 0; k < 64; ++k) {
      const float4 g0 = *(const float4*)&Gs[k][i0];
      const float4 g1 = *(const float4*)&Gs[k][i0 + 4];
      const float4 xv = *(const float4*)&XT[k][la];
      const float ga[8] = {g0.x, g0.y, g0.z, g0.w, g1.x, g1.y, g1.z, g1.w};
      const float xa[4] = {xv.x, xv.y, xv.z, xv.w};
      #pragma unroll
      for (int a = 0; a < 8; ++a)
        #pragma unroll
        for (int lv = 0; lv < 4; ++lv)
          acc[a][lv] += ga[a] * xa[lv];
    }
    #pragma unroll
    for (int lv = 0; lv < 4; ++lv) {
      float s = 0.f;
      #pragma unroll
      for (int a = 0; a < 8; ++a)
        s += XT[i0 + a][la + lv] * (acc[a][lv] + 2.0f * wsh[i0 + a]);
      n2p[t & 7][la + lv] = s;
    }
  }
  __syncthreads();
  if (t < LT) {
    float n2 = bb;
    #pragma unroll
    for (int p = 0; p < 8; ++p) n2 += n2p[p][t];
    n2 = fmaxf(n2, 0.0f);
    const float d1 = 1.0f / fmaxf(sqrtf(n2), 1e-12f);
    d1s[t] = d1;
    d2s[t] = d1 * d1;
  }
  __syncthreads();

  float sg1 = 0.f, sg2 = 0.f;
  if (t < 64) {
    float a1 = d1s[t] + d1s[t + 64];
    float a2 = d2s[t] + d2s[t + 64];
    #pragma unroll
    for (int off = 32; off > 0; off >>= 1) {
      a1 += __shfl_down(a1, off, 64);
      a2 += __shfl_down(a2, off, 64);
    }
    sg1 = a1; sg2 = a2;
  }

  // phase B: A1/A2 4x4 per-thread accumulation over the tile
  const int bi0 = (t >> 4) * 4;
  const int bj0 = (t & 15) * 4;
  float A1a[4][4] = {}, A2a[4][4] = {};
  float u1a[4] = {0.f, 0.f, 0.f, 0.f}, u2a[4] = {0.f, 0.f, 0.f, 0.f};
  for (int l4 = 0; l4 < LT; l4 += 4) {
    const float4 q1 = *(const float4*)&d1s[l4];
    const float4 q2 = *(const float4*)&d2s[l4];
    const float d1v[4] = {q1.x, q1.y, q1.z, q1.w};
    const float d2v[4] = {q2.x, q2.y, q2.z, q2.w};
    float e1[4][4], e2[4][4], xj[4][4];
    #pragma unroll
    for (int a = 0; a < 4; ++a) {
      const float4 xv = *(const float4*)&XT[bi0 + a][l4];
      const float xa[4] = {xv.x, xv.y, xv.z, xv.w};
      #pragma unroll
      for (int lv = 0; lv < 4; ++lv) {
        e1[a][lv] = d1v[lv] * xa[lv];
        e2[a][lv] = d2v[lv] * xa[lv];
      }
    }
    #pragma unroll
    for (int bq = 0; bq < 4; ++bq) {
      const float4 xv = *(const float4*)&XT[bj0 + bq][l4];
      xj[bq][0] = xv.x; xj[bq][1] = xv.y; xj[bq][2] = xv.z; xj[bq][3] = xv.w;
    }
    #pragma unroll
    for (int a = 0; a < 4; ++a)
      #pragma unroll
      for (int bq = 0; bq < 4; ++bq) {
        float s1 = A1a[a][bq], s2 = A2a[a][bq];
        #pragma unroll
        for (int lv = 0; lv < 4; ++lv) {
          s1 += e1[a][lv] * xj[bq][lv];
          s2 += e2[a][lv] * xj[bq][lv];
        }
        A1a[a][bq] = s1; A2a[a][bq] = s2;
      }
    if (bj0 == 0) {
      #pragma unroll
      for (int a = 0; a < 4; ++a)
        #pragma unroll
        for (int lv = 0; lv < 4; ++lv) {
          u1a[a] += e1[a][lv];
          u2a[a] += e2[a][lv];
        }
    }
  }

  float* P = ws + OFF_STATS + (size_t)blk * PS;
  #pragma unroll
  for (int a = 0; a < 4; ++a)
    #pragma unroll
    for (int bq = 0; bq < 4; ++bq) {
      P[(bi0 + a) * 64 + bj0 + bq] = A1a[a][bq];
      P[4096 + (bi0 + a) * 64 + bj0 + bq] = A2a[a][bq];
    }
  if (bj0 == 0) {
    #pragma unroll
    for (int a = 0; a < 4; ++a) {
      P[8192 + bi0 + a] = u1a[a];
      P[8256 + bi0 + a] = u2a[a];
    }
  }
  if (t == 0) { P[8320] = sg1; P[8321] = sg2; }
}

// ---------------------------------------------------------------------------
// k1b: reduce 64 partials per batch -> A1R, A2R, U1R, U2R, SIG
// grid 256 (= b(8) x sel(2) x q(16)) x 256
__global__ __launch_bounds__(256) void k1b_reduce(float* __restrict__ ws) {
  const int t = threadIdx.x;
  const int blk = blockIdx.x;
  const int b = blk >> 5, sel = (blk >> 4) & 1, q = blk & 15;
  const float* SB = ws + OFF_STATS + (size_t)b * 64 * PS + (size_t)sel * 4096;
  float* dst = ws + (sel ? OFF_A2R : OFF_A1R) + (size_t)b * 4096;
  const int e = q * 256 + t;
  float s = 0.f;
  #pragma unroll 8
  for (int p = 0; p < 64; ++p) s += SB[(size_t)p * PS + e];
  dst[e] = s;
  if (sel == 0 && q == 0) {
    const float* UB = ws + OFF_STATS + (size_t)b * 64 * PS;
    if (t < 64) {
      float s2 = 0.f;
      #pragma unroll 8
      for (int p = 0; p < 64; ++p) s2 += UB[(size_t)p * PS + 8192 + t];
      ws[OFF_U1R + b * 64 + t] = s2;
    } else if (t < 128) {
      const int i = t - 64;
      float s2 = 0.f;
      #pragma unroll 8
      for (int p = 0; p < 64; ++p) s2 += UB[(size_t)p * PS + 8256 + i];
      ws[OFF_U2R + b * 64 + i] = s2;
    } else if (t == 128) {
      float s1 = 0.f, s2 = 0.f;
      for (int p = 0; p < 64; ++p) {
        s1 += UB[(size_t)p * PS + 8320];
        s2 += UB[(size_t)p * PS + 8321];
      }
      ws[OFF_SIG + b * 2] = s1;
      ws[OFF_SIG + b * 2 + 1] = s2;
    }
  }
}

// ---------------------------------------------------------------------------
// k2a: T2 = A2 @ Wk, T1 = A1 @ Wv; p1 = Wk^T u1, p2 = Wk^T u2, q1 = Wv^T u1
// grid 128 (= b(8) x wsel(2) x hstrip(8)) x 256
__global__ __launch_bounds__(256) void k2a_T(const float* __restrict__ Wk,
                                             const float* __restrict__ Wv,
                                             float* __restrict__ ws) {
  __shared__ __align__(16) float A[64][65];
  const int t = threadIdx.x;
  const int blk = blockIdx.x;
  const int b = blk >> 4, wsel = (blk >> 3) & 1, hstrip = blk & 7;
  const int hs0 = hstrip * 64;
  const float* Ar = ws + (wsel ? OFF_A1R : OFF_A2R) + (size_t)b * 4096;
  for (int k = 0; k < 16; ++k) {
    const int e = k * 256 + t;
    A[e >> 6][e & 63] = Ar[e];
  }
  __syncthreads();
  const float* W = wsel ? Wv : Wk;
  float* T = ws + (wsel ? OFF_T1 : OFF_T2) + (size_t)b * 64 * Hn;
  const int ti = t >> 4, th = t & 15;
  float acc[4][4] = {};
  for (int j = 0; j < 64; ++j) {
    float av[4];
    #pragma unroll
    for (int a = 0; a < 4; ++a) av[a] = A[ti * 4 + a][j];
    #pragma unroll
    for (int hb = 0; hb < 4; ++hb) {
      const float wv = W[(size_t)j * Hn + hs0 + hb * 16 + th];
      #pragma unroll
      for (int a = 0; a < 4; ++a) acc[a][hb] += av[a] * wv;
    }
  }
  #pragma unroll
  for (int a = 0; a < 4; ++a)
    #pragma unroll
    for (int hb = 0; hb < 4; ++hb)
      T[(size_t)(ti * 4 + a) * Hn + hs0 + hb * 16 + th] = acc[a][hb];

  // rank-1 helper vectors, each block handles its own 64-h strip
  if (t < 64) {
    const int h = hs0 + t;
    const float* u1r = ws + OFF_U1R + b * 64;
    const float* u2r = ws + OFF_U2R + b * 64;
    if (wsel == 0) {
      float s1 = 0.f, s2 = 0.f;
      #pragma unroll 8
      for (int i = 0; i < 64; ++i) {
        const float wv = Wk[(size_t)i * Hn + h];
        s1 += wv * u1r[i];
        s2 += wv * u2r[i];
      }
      ws[OFF_P1 + b * Hn + h] = s1;
      ws[OFF_P2 + b * Hn + h] = s2;
    } else {
      float s = 0.f;
      #pragma unroll 8
      for (int i = 0; i < 64; ++i) s += Wv[(size_t)i * Hn + h] * u1r[i];
      ws[OFF_Q1 + b * Hn + h] = s;
    }
  }
}

// ---------------------------------------------------------------------------
// k3: U partials = T2 @ C (16 h-chunks of 32), plus c1 = bk^T C, g = p2^T C
// grid 512 (= b(8) x hc(16) x ds(4)) x 256
__global__ __launch_bounds__(256) void k3_U(const float* __restrict__ C,
                                            const float* __restrict__ bk,
                                            float* __restrict__ ws) {
  __shared__ __align__(16) float T2s[64][36];   // [i][h within chunk], row 144B (16B-aligned)
  const int t = threadIdx.x;
  const int blk = blockIdx.x;
  const int b = blk >> 6;
  const int hc = (blk >> 2) & 15;
  const int ds = blk & 3;
  const int h0 = hc * 32;
  const int d04 = ds * 32;                      // float4 offset of 128-wide d strip
  const float4* T24 = (const float4*)(ws + OFF_T2 + (size_t)b * 64 * Hn);
  #pragma unroll
  for (int p = 0; p < 2; ++p) {
    const int idx = p * 256 + t;                // 512 float4 total
    const int r = idx >> 3, c4 = idx & 7;
    *(float4*)&T2s[r][c4 * 4] = T24[(size_t)r * 128 + (h0 >> 2) + c4];
  }
  __syncthreads();

  const int dd4 = t & 31;
  const int ig = t >> 5;
  const int i0 = ig * 8;
  const float4* C4 = (const float4*)(C + (size_t)b * Hn * Hn);
  const float* p2 = ws + OFF_P2 + (size_t)b * Hn;

  float4 acc[8];
  #pragma unroll
  for (int a = 0; a < 8; ++a) acc[a] = make_float4(0.f, 0.f, 0.f, 0.f);
  float4 c1a = make_float4(0.f, 0.f, 0.f, 0.f);
  float4 ga  = make_float4(0.f, 0.f, 0.f, 0.f);

  #pragma unroll 4
  for (int hh = 0; hh < 32; ++hh) {
    const float4 cv = C4[(size_t)(h0 + hh) * 128 + d04 + dd4];
    #pragma unroll
    for (int a = 0; a < 8; ++a) {
      const float w = T2s[i0 + a][hh];
      acc[a].x += w * cv.x; acc[a].y += w * cv.y;
      acc[a].z += w * cv.z; acc[a].w += w * cv.w;
    }
    if (ig == 0) {
      const float bkh = bk[h0 + hh], p2h = p2[h0 + hh];
      c1a.x += bkh * cv.x; c1a.y += bkh * cv.y; c1a.z += bkh * cv.z; c1a.w += bkh * cv.w;
      ga.x  += p2h * cv.x; ga.y  += p2h * cv.y; ga.z  += p2h * cv.z; ga.w  += p2h * cv.w;
    }
  }

  float4* Up4 = (float4*)(ws + OFF_UP) + (size_t)(b * NH3 + hc) * 64 * 128;
  #pragma unroll
  for (int a = 0; a < 8; ++a)
    Up4[(size_t)(i0 + a) * 128 + d04 + dd4] = acc[a];
  if (ig == 0) {
    float4* c1p4 = (float4*)(ws + OFF_C1P + (size_t)(b * NH3 + hc) * Hn);
    float4* gp4  = (float4*)(ws + OFF_GP  + (size_t)(b * NH3 + hc) * Hn);
    c1p4[d04 + dd4] = c1a;
    gp4[d04 + dd4] = ga;
  }
}

// ---------------------------------------------------------------------------
// k3b: Td = T1 - sum_q Up[q]  (elementwise, float4)
// grid 256 x 256
__global__ __launch_bounds__(256) void k3b_td(float* __restrict__ ws) {
  const int f = blockIdx.x * 256 + threadIdx.x;   // float4 index, 65536 total
  const int b = f >> 13;
  const int r4 = f & 8191;
  const float4* T14 = (const float4*)(ws + OFF_T1);
  const float4* Up4 = (const float4*)(ws + OFF_UP);
  float4 v = T14[f];
  #pragma unroll
  for (int q = 0; q < NH3; ++q) {
    const float4 u = Up4[(size_t)(b * NH3 + q) * 8192 + r4];
    v.x -= u.x; v.y -= u.y; v.z -= u.z; v.w -= u.w;
  }
  ((float4*)(ws + OFF_TD))[f] = v;
}

// ---------------------------------------------------------------------------
// k4: out = C + Wk^T Td + (p1 + sig1*bk) (x) bv + bk (x) (q1 - g - sig2*c1) - p2 (x) c1
// grid 256 (= b(8) x hstrip(8, 64-wide) x dstrip(4, 128-wide)) x 256
__global__ __launch_bounds__(256) void k4_out(const float* __restrict__ C,
                                              const float* __restrict__ Wk,
                                              const float* __restrict__ bk,
                                              const float* __restrict__ bv,
                                              const float* __restrict__ ws,
                                              float* __restrict__ out) {
  __shared__ __align__(16) float Tds[64][132];
  __shared__ __align__(16) float Wks[64][68];
  __shared__ float phs[64], bks[64], p2s[64];
  __shared__ float bvs[128], terms[128], c1s[128];

  const int t = threadIdx.x;
  const int blk = blockIdx.x;
  const int b = blk >> 5;
  const int hs0 = ((blk >> 2) & 7) * 64;
  const int d04 = (blk & 3) * 32;               // float4 offset of 128-wide d strip
  const float sg1 = ws[OFF_SIG + b * 2];
  const float sg2 = ws[OFF_SIG + b * 2 + 1];

  const float4* TdG4 = (const float4*)(ws + OFF_TD + (size_t)b * 64 * Hn);
  #pragma unroll
  for (int p = 0; p < 8; ++p) {
    const int idx = p * 256 + t;                // 2048 float4
    const int r = idx >> 5, c4 = idx & 31;
    *(float4*)&Tds[r][c4 * 4] = TdG4[(size_t)r * 128 + d04 + c4];
  }
  const float4* Wk4 = (const float4*)Wk;
  #pragma unroll
  for (int p = 0; p < 4; ++p) {
    const int idx = p * 256 + t;                // 1024 float4
    const int r = idx >> 4, c4 = idx & 15;
    *(float4*)&Wks[r][c4 * 4] = Wk4[(size_t)r * 128 + (hs0 >> 2) + c4];
  }
  if (t < 64) {
    const int h = hs0 + t;
    const float bkv = bk[h];
    bks[t] = bkv;
    phs[t] = ws[OFF_P1 + (size_t)b * Hn + h] + sg1 * bkv;
    p2s[t] = ws[OFF_P2 + (size_t)b * Hn + h];
  } else if (t < 192) {
    const int dd = t - 64;
    const int d = d04 * 4 + dd;
    float c1 = 0.f, g = 0.f;
    #pragma unroll
    for (int q = 0; q < NH3; ++q) {
      c1 += ws[OFF_C1P + (size_t)(b * NH3 + q) * Hn + d];
      g  += ws[OFF_GP  + (size_t)(b * NH3 + q) * Hn + d];
    }
    c1s[dd] = c1;
    bvs[dd] = bv[d];
    terms[dd] = ws[OFF_Q1 + (size_t)b * Hn + d] - g - sg2 * c1;
  }
  __syncthreads();

  const int ti = t >> 5;   // rows hh = ti*8 .. +8
  const int tj4 = t & 31;  // d float4 within strip
  float4 acc[8];
  #pragma unroll
  for (int a = 0; a < 8; ++a) acc[a] = make_float4(0.f, 0.f, 0.f, 0.f);
  for (int j = 0; j < 64; ++j) {
    const float4 td4 = *(const float4*)&Tds[j][tj4 * 4];
    #pragma unroll
    for (int a = 0; a < 8; ++a) {
      const float wv = Wks[j][ti * 8 + a];
      acc[a].x += wv * td4.x; acc[a].y += wv * td4.y;
      acc[a].z += wv * td4.z; acc[a].w += wv * td4.w;
    }
  }

  const float4* C4b = (const float4*)(C + (size_t)b * Hn * Hn);
  float4* out4 = (float4*)(out + (size_t)b * Hn * Hn);
  const float4 bv4 = *(const float4*)&bvs[tj4 * 4];
  const float4 tm4 = *(const float4*)&terms[tj4 * 4];
  const float4 c14 = *(const float4*)&c1s[tj4 * 4];
  #pragma unroll
  for (int a = 0; a < 8; ++a) {
    const int hh = ti * 8 + a;
    const int h = hs0 + hh;
    const float4 c = C4b[(size_t)h * 128 + d04 + tj4];
    const float ph = phs[hh], bkh = bks[hh], p2h = p2s[hh];
    float4 o;
    o.x = c.x + acc[a].x + ph * bv4.x + bkh * tm4.x - p2h * c14.x;
    o.y = c.y + acc[a].y + ph * bv4.y + bkh * tm4.y - p2h * c14.y;
    o.z = c.z + acc[a].z + ph * bv4.z + bkh * tm4.z - p2h * c14.z;
    o.w = c.w + acc[a].w + ph * bv4.w + bkh * tm4.w - p2h * c14.w;
    out4[(size_t)h * 128 + d04 + tj4] = o;
  }
}

// ---------------------------------------------------------------------------
extern "C" void kernel_launch(void* const* d_in, const int* in_sizes, int n_in,
                              void* d_out, int out_size, void* d_ws, size_t ws_size,
                              hipStream_t stream) {
  const float* hs = (const float*)d_in[0];
  const float* C  = (const float*)d_in[1];
  const float* Wk = (const float*)d_in[2];
  const float* bk = (const float*)d_in[3];
  const float* Wv = (const float*)d_in[4];
  const float* bv = (const float*)d_in[5];
  float* out = (float*)d_out;
  float* ws = (float*)d_ws;
  (void)in_sizes; (void)n_in; (void)out_size; (void)ws_size;

  hipLaunchKernelGGL(k0_pre,     dim3(17),  dim3(256), 0, stream, Wk, bk, ws);
  hipLaunchKernelGGL(k1_stats,   dim3(512), dim3(256), 0, stream, hs, ws);
  hipLaunchKernelGGL(k1b_reduce, dim3(256), dim3(256), 0, stream, ws);
  hipLaunchKernelGGL(k2a_T,      dim3(128), dim3(256), 0, stream, Wk, Wv, ws);
  hipLaunchKernelGGL(k3_U,       dim3(512), dim3(256), 0, stream, C, bk, ws);
  hipLaunchKernelGGL(k3b_td,     dim3(256), dim3(256), 0, stream, ws);
  hipLaunchKernelGGL(k4_out,     dim3(256), dim3(256), 0, stream, C, Wk, bk, bv, ws, out);
}